// Round 1
// baseline (2763.424 us; speedup 1.0000x reference)
//
#include <hip/hip_runtime.h>
#include <hip/hip_bf16.h>

typedef __attribute__((ext_vector_type(8))) short short8;
typedef __attribute__((ext_vector_type(4))) short short4v;
typedef __attribute__((ext_vector_type(4))) float floatx4;
typedef __attribute__((ext_vector_type(4))) unsigned int uint4v;

using bf16 = __hip_bfloat16;

#define DEVI __device__ __forceinline__

// ---------------- workspace layout (bytes) ----------------
static constexpr size_t OFF_SCORE  = 0;                        // 128*128 f32
static constexpr size_t OFF_CTR    = OFF_SCORE  + 65536;       // 8*128 u32
static constexpr size_t OFF_CPUB0  = OFF_CTR    + 4096;        // 128*1024 bf16
static constexpr size_t OFF_CPUB1  = OFF_CPUB0  + 262144;
static constexpr size_t ZERO_BYTES = OFF_CPUB1;                // score+ctr+Cpub0 zeroed
static constexpr size_t OFF_G      = OFF_CPUB1  + 262144;      // 128*128 f32
static constexpr size_t OFF_BIASR  = OFF_G      + 65536;       // 1024 f32
static constexpr size_t OFF_CFIN   = OFF_BIASR  + 4096;        // 128*1024 f32
static constexpr size_t OFF_CONCAT = OFF_CFIN   + 524288;      // 128*3072 bf16
static constexpr size_t OFF_FACTS  = OFF_CONCAT + 786432;      // 16M bf16
static constexpr size_t OFF_WZ1    = OFF_FACTS  + 33554432ull; // 1024*4096 bf16
static constexpr size_t OFF_WRW    = OFF_WZ1    + 8388608ull;  // 2048*1024 bf16
static constexpr size_t OFF_URU    = OFF_WRW    + 4194304ull;  // 2048*1024 bf16
static constexpr size_t OFF_WM     = OFF_URU    + 4194304ull;  // 1024*3072 bf16
static constexpr size_t OFF_P      = OFF_WM     + 6291456ull;  // 128*128*2048 bf16

DEVI float sigm_f(float x){ return 1.f/(1.f + __expf(-x)); }
DEVI float tanh_f(float x){ float e = __expf(2.f*x); return 1.f - 2.f/(e + 1.f); }

// ---------------- small utility kernels ----------------
__global__ void cast_f32_bf16(const float* __restrict__ src, bf16* __restrict__ dst, int n){
  int i = (blockIdx.x*256 + threadIdx.x)*4;
  if (i >= n) return;
  float4 v = *(const float4*)(src + i);
  union { bf16 h[4]; short4v s; } u;
  u.h[0] = __float2bfloat16(v.x); u.h[1] = __float2bfloat16(v.y);
  u.h[2] = __float2bfloat16(v.z); u.h[3] = __float2bfloat16(v.w);
  *(short4v*)(dst + i) = u.s;
}

__global__ void add_bias_k(const float* __restrict__ a, const float* __restrict__ b, float* __restrict__ o){
  int i = blockIdx.x*256 + threadIdx.x;
  if (i < 1024) o[i] = a[i] + b[i];
}

__global__ void softmax128(const float* __restrict__ score, float* __restrict__ G){
  int b = blockIdx.x, t = threadIdx.x;
  int lane = t & 63, wv = t >> 6;
  float v = score[b*128 + t];
  float mx = v;
  #pragma unroll
  for (int m = 1; m < 64; m <<= 1) mx = fmaxf(mx, __shfl_xor(mx, m));
  __shared__ float r1[2], r2[2];
  if (lane == 0) r1[wv] = mx;
  __syncthreads();
  mx = fmaxf(r1[0], r1[1]);
  float e = __expf(v - mx);
  float sm = e;
  #pragma unroll
  for (int m = 1; m < 64; m <<= 1) sm += __shfl_xor(sm, m);
  if (lane == 0) r2[wv] = sm;
  __syncthreads();
  sm = r2[0] + r2[1];
  G[b*128 + t] = e / sm;
}

__global__ void build_concat(const float* __restrict__ prevM, const float* __restrict__ Cfin,
                             const float* __restrict__ q, bf16* __restrict__ out){
  int i = (blockIdx.x*256 + threadIdx.x)*4;   // n = 128*3072
  if (i >= 128*3072) return;
  int b = i / 3072, k = i % 3072;
  const float* src = (k < 1024) ? (prevM + b*1024 + k)
                   : (k < 2048) ? (Cfin + b*1024 + (k-1024))
                                : (q    + b*1024 + (k-2048));
  float4 v = *(const float4*)src;
  union { bf16 h[4]; short4v s; } u;
  u.h[0] = __float2bfloat16(v.x); u.h[1] = __float2bfloat16(v.y);
  u.h[2] = __float2bfloat16(v.z); u.h[3] = __float2bfloat16(v.w);
  *(short4v*)(out + i) = u.s;
}

// ---------------- gate GEMM: z on-the-fly, fused tanh + Wz2 reduction ----------------
// grid (8, 128): blockIdx.y = batch b (M-tile of 128 s-rows), blockIdx.x = N-tile
__global__ __launch_bounds__(256, 2) void gate_gemm(
    const float* __restrict__ facts, const float* __restrict__ q,
    const float* __restrict__ pm, const bf16* __restrict__ Wz1b,
    const float* __restrict__ bz1, const float* __restrict__ wz2,
    float* __restrict__ score)
{
  constexpr int TS = 80;                    // padded LDS stride (16B-aligned, breaks bank alias)
  __shared__ bf16 As[128*TS];
  __shared__ bf16 Bs[128*TS];
  __shared__ float qs[1024];
  __shared__ float ms[1024];
  int tid = threadIdx.x;
  int b  = blockIdx.y;
  int n0 = blockIdx.x * 128;
  int w = tid >> 6, lane = tid & 63;
  int wm = w >> 1, wn = w & 1;
  int quad = lane >> 4, col = lane & 15;

  for (int i = tid; i < 1024; i += 256){ qs[i] = q[b*1024 + i]; ms[i] = pm[b*1024 + i]; }
  __syncthreads();

  floatx4 acc[4][4];
  #pragma unroll
  for (int a = 0; a < 4; ++a)
    #pragma unroll
    for (int c = 0; c < 4; ++c) acc[a][c] = (floatx4){0.f,0.f,0.f,0.f};

  for (int it = 0; it < 64; ++it){
    int k0 = it * 64;
    int qd = k0 >> 10;          // quadrant of z (uniform per iter)
    int kk0 = k0 & 1023;
    // stage A: build z tile in VALU
    #pragma unroll
    for (int i = 0; i < 4; ++i){
      int c = tid + i*256;
      int r = c >> 3, cc = c & 7;
      int kk = kk0 + cc*8;
      const float* fp = facts + (size_t)(b*128 + r)*1024 + kk;
      float f[8], aux[8];
      *(float4*)(f)   = *(const float4*)(fp);
      *(float4*)(f+4) = *(const float4*)(fp + 4);
      const float* av = (qd == 0 || qd == 2) ? qs : ms;
      *(float4*)(aux)   = *(const float4*)(av + kk);
      *(float4*)(aux+4) = *(const float4*)(av + kk + 4);
      union { bf16 h[8]; short8 s8; } u;
      if (qd < 2){
        #pragma unroll
        for (int j = 0; j < 8; ++j) u.h[j] = __float2bfloat16(f[j]*aux[j]);
      } else {
        #pragma unroll
        for (int j = 0; j < 8; ++j) u.h[j] = __float2bfloat16(fabsf(f[j]-aux[j]));
      }
      *(short8*)&As[r*TS + cc*8] = u.s8;
    }
    // stage B (Wz1 bf16, B^T layout, ldb=4096)
    #pragma unroll
    for (int i = 0; i < 4; ++i){
      int c = tid + i*256;
      int r = c >> 3, cc = c & 7;
      *(uint4v*)&Bs[r*TS + cc*8] = *(const uint4v*)(Wz1b + (size_t)(n0 + r)*4096 + k0 + cc*8);
    }
    __syncthreads();
    #pragma unroll
    for (int kt = 0; kt < 2; ++kt){
      short8 af[4], bfv[4];
      #pragma unroll
      for (int mt = 0; mt < 4; ++mt)
        af[mt] = *(const short8*)&As[(wm*64 + mt*16 + col)*TS + kt*32 + quad*8];
      #pragma unroll
      for (int nt = 0; nt < 4; ++nt)
        bfv[nt] = *(const short8*)&Bs[(wn*64 + nt*16 + col)*TS + kt*32 + quad*8];
      #pragma unroll
      for (int mt = 0; mt < 4; ++mt)
        #pragma unroll
        for (int nt = 0; nt < 4; ++nt)
          acc[mt][nt] = __builtin_amdgcn_mfma_f32_16x16x32_bf16(af[mt], bfv[nt], acc[mt][nt], 0,0,0);
    }
    __syncthreads();
  }
  // epilogue: tanh(acc + bz1) * wz2, reduce over this wave's 64 n-cols, atomicAdd to score
  #pragma unroll
  for (int mt = 0; mt < 4; ++mt){
    float part[4] = {0.f,0.f,0.f,0.f};
    #pragma unroll
    for (int nt = 0; nt < 4; ++nt){
      int n = n0 + wn*64 + nt*16 + col;
      float b1 = bz1[n], w2 = wz2[n];
      #pragma unroll
      for (int rr = 0; rr < 4; ++rr)
        part[rr] += tanh_f(acc[mt][nt][rr] + b1) * w2;
    }
    #pragma unroll
    for (int rr = 0; rr < 4; ++rr){
      float p = part[rr];
      p += __shfl_xor(p, 1); p += __shfl_xor(p, 2);
      p += __shfl_xor(p, 4); p += __shfl_xor(p, 8);
      if (col == 0)
        atomicAdd(&score[b*128 + wm*64 + mt*16 + quad*4 + rr], p);
    }
  }
}

// ---------------- generic 128x128 bf16 GEMM (B^T layout) ----------------
// MODE 0: store P[s][b][n] bf16 (proj).  MODE 1: out = relu(acc + bias) fp32 (final).
template<int MODE>
__global__ __launch_bounds__(256, 2) void gemm_bt(
    const bf16* __restrict__ A, const bf16* __restrict__ Bm, int K,
    bf16* __restrict__ Pout, const float* __restrict__ bias, float* __restrict__ out)
{
  constexpr int TS = 80;
  __shared__ bf16 As[128*TS];
  __shared__ bf16 Bs[128*TS];
  int tid = threadIdx.x;
  int m0 = blockIdx.y * 128, n0 = blockIdx.x * 128;
  int w = tid >> 6, lane = tid & 63;
  int wm = w >> 1, wn = w & 1;
  int quad = lane >> 4, col = lane & 15;

  floatx4 acc[4][4];
  #pragma unroll
  for (int a = 0; a < 4; ++a)
    #pragma unroll
    for (int c = 0; c < 4; ++c) acc[a][c] = (floatx4){0.f,0.f,0.f,0.f};

  int nkb = K >> 6;
  for (int it = 0; it < nkb; ++it){
    int k0 = it * 64;
    #pragma unroll
    for (int i = 0; i < 4; ++i){
      int c = tid + i*256;
      int r = c >> 3, cc = c & 7;
      *(uint4v*)&As[r*TS + cc*8] = *(const uint4v*)(A  + (size_t)(m0 + r)*K + k0 + cc*8);
      *(uint4v*)&Bs[r*TS + cc*8] = *(const uint4v*)(Bm + (size_t)(n0 + r)*K + k0 + cc*8);
    }
    __syncthreads();
    #pragma unroll
    for (int kt = 0; kt < 2; ++kt){
      short8 af[4], bfv[4];
      #pragma unroll
      for (int mt = 0; mt < 4; ++mt)
        af[mt] = *(const short8*)&As[(wm*64 + mt*16 + col)*TS + kt*32 + quad*8];
      #pragma unroll
      for (int nt = 0; nt < 4; ++nt)
        bfv[nt] = *(const short8*)&Bs[(wn*64 + nt*16 + col)*TS + kt*32 + quad*8];
      #pragma unroll
      for (int mt = 0; mt < 4; ++mt)
        #pragma unroll
        for (int nt = 0; nt < 4; ++nt)
          acc[mt][nt] = __builtin_amdgcn_mfma_f32_16x16x32_bf16(af[mt], bfv[nt], acc[mt][nt], 0,0,0);
    }
    __syncthreads();
  }
  #pragma unroll
  for (int mt = 0; mt < 4; ++mt)
    #pragma unroll
    for (int nt = 0; nt < 4; ++nt)
      #pragma unroll
      for (int rr = 0; rr < 4; ++rr){
        int m = m0 + wm*64 + mt*16 + quad*4 + rr;
        int n = n0 + wn*64 + nt*16 + col;
        float v = acc[mt][nt][rr];
        if (MODE == 0){
          // m = b*128 + s  ->  P[s][b][n]
          Pout[((size_t)(m & 127)*128 + (m >> 7))*2048 + n] = __float2bfloat16(v);
        } else {
          out[(size_t)m*1024 + n] = fmaxf(v + bias[n], 0.f);
        }
      }
}

// ---------------- the sequential scan ----------------
// 256 blocks = 8 batch-groups (16 batches each) x 32 column-blocks (32 cols each).
// Weights (Ur,U rows for this block's columns) live in registers as B-fragments.
// C master fp32 in registers; bf16 copy double-buffered through global (Cpub).
__global__ __launch_bounds__(256, 1) void scan_kernel(
    const bf16* __restrict__ UrU, const bf16* __restrict__ P,
    const float* __restrict__ G, const float* __restrict__ bias_r,
    const float* __restrict__ bw, const float* __restrict__ bu,
    bf16* __restrict__ Cpub, float* __restrict__ Cfinal,
    unsigned int* __restrict__ counters)
{
  constexpr int CS = 1040;               // padded stride (bf16 elems), 16B-aligned
  __shared__ bf16 Cs[16*CS];             // staged C for this batch-group
  __shared__ float Qex[2*16*32];         // Q1 / Q2 exchange tiles
  int tid = threadIdx.x;
  int g  = blockIdx.x >> 5;              // batch group 0..7
  int nb = blockIdx.x & 31;              // column block 0..31
  int b0 = g * 16, j0 = nb * 32;
  int w = tid >> 6, lane = tid & 63;
  int quad = lane >> 4, col = lane & 15;

  // wave w: matrix (w>>1): 0 -> Ur (Q1), 1 -> U (Q2); n-half (w&1)
  short8 bfrag[32];
  {
    int n = ((w >> 1) << 10) + j0 + ((w & 1) << 4) + col;
    const bf16* src = UrU + (size_t)n*1024 + (quad << 3);
    #pragma unroll
    for (int kt = 0; kt < 32; ++kt) bfrag[kt] = *(const short8*)(src + kt*32);
  }

  int jj = tid & 31;
  int r0 = tid >> 5, r1 = r0 + 8;        // two batch rows per thread
  float C0 = 0.f, C1 = 0.f;
  float brv = bias_r[j0 + jj], bwv = bw[j0 + jj], buv = bu[j0 + jj];
  unsigned int* ctr = counters + g*128;

  for (int s = 0; s < 128; ++s){
    // stage this group's C (16 x 1024 bf16) from the publish buffer
    const bf16* Cg = Cpub + (size_t)(s & 1)*(128*1024) + b0*1024;
    #pragma unroll
    for (int i = 0; i < 8; ++i){
      int c = tid + (i << 8);
      int r = c >> 7, cc = c & 127;
      *(uint4v*)&Cs[r*CS + cc*8] = *(const uint4v*)(Cg + r*1024 + cc*8);
    }
    __syncthreads();
    // Q = C @ [Ur;U]^T restricted to this block's columns
    floatx4 acc = (floatx4){0.f,0.f,0.f,0.f};
    {
      const bf16* Ap = Cs + col*CS + (quad << 3);
      #pragma unroll
      for (int kt = 0; kt < 32; ++kt){
        short8 a = *(const short8*)(Ap + kt*32);
        acc = __builtin_amdgcn_mfma_f32_16x16x32_bf16(a, bfrag[kt], acc, 0,0,0);
      }
    }
    {
      int row = quad << 2, c2 = ((w & 1) << 4) + col;
      float* qx = Qex + ((w >> 1) << 9);
      #pragma unroll
      for (int rr = 0; rr < 4; ++rr) qx[(row + rr)*32 + c2] = acc[rr];
    }
    __syncthreads();
    // elementwise GRU-style update, two (batch,col) elements per thread
    const bf16* Ps = P + (size_t)s*(128*2048);
    float g0 = G[(b0 + r0)*128 + s], g1 = G[(b0 + r1)*128 + s];
    float p1a = __bfloat162float(Ps[(b0 + r0)*2048 + j0 + jj]);
    float p2a = __bfloat162float(Ps[(b0 + r0)*2048 + 1024 + j0 + jj]);
    float p1b = __bfloat162float(Ps[(b0 + r1)*2048 + j0 + jj]);
    float p2b = __bfloat162float(Ps[(b0 + r1)*2048 + 1024 + j0 + jj]);
    float q1a = Qex[r0*32 + jj], q2a = Qex[512 + r0*32 + jj];
    float q1b = Qex[r1*32 + jj], q2b = Qex[512 + r1*32 + jj];
    float ra = sigm_f(p1a + q1a + brv);
    float ha = tanh_f(p2a + bwv + ra*(q2a + buv));
    C0 = g0*ha + (1.f - g0)*C0;
    float rb = sigm_f(p1b + q1b + brv);
    float hb = tanh_f(p2b + bwv + rb*(q2b + buv));
    C1 = g1*hb + (1.f - g1)*C1;
    bf16* Cn = Cpub + (size_t)((s & 1) ^ 1)*(128*1024);
    Cn[(b0 + r0)*1024 + j0 + jj] = __float2bfloat16(C0);
    Cn[(b0 + r1)*1024 + j0 + jj] = __float2bfloat16(C1);
    if (s != 127){
      // group barrier: release fence -> flag -> acquire fence
      __syncthreads();                     // drains each wave's stores (vmcnt) pre-barrier
      if (tid == 0){
        __threadfence();                   // make C stores device-visible
        atomicAdd(&ctr[s], 1u);
        while (__hip_atomic_load(&ctr[s], __ATOMIC_RELAXED, __HIP_MEMORY_SCOPE_AGENT) < 32u)
          __builtin_amdgcn_s_sleep(2);
        __threadfence();                   // invalidate stale caches before next read
      }
      __syncthreads();
    }
  }
  Cfinal[(b0 + r0)*1024 + j0 + jj] = C0;
  Cfinal[(b0 + r1)*1024 + j0 + jj] = C1;
}

// ---------------- host launch ----------------
extern "C" void kernel_launch(void* const* d_in, const int* in_sizes, int n_in,
                              void* d_out, int out_size, void* d_ws, size_t ws_size,
                              hipStream_t stream) {
  const float* facts     = (const float*)d_in[0];
  const float* questions = (const float*)d_in[1];
  const float* prevM     = (const float*)d_in[2];
  const float* Wr        = (const float*)d_in[3];
  const float* br        = (const float*)d_in[4];
  const float* Ur        = (const float*)d_in[5];
  const float* bur       = (const float*)d_in[6];
  const float* Wf        = (const float*)d_in[7];
  const float* bw        = (const float*)d_in[8];
  const float* U         = (const float*)d_in[9];
  const float* bu        = (const float*)d_in[10];
  const float* Wz1       = (const float*)d_in[11];
  const float* bz1       = (const float*)d_in[12];
  const float* Wz2       = (const float*)d_in[13];
  // d_in[14] = bz2: constant shift, cancels in softmax
  const float* Wm        = (const float*)d_in[15];
  const float* bm        = (const float*)d_in[16];
  float* out = (float*)d_out;

  char* ws = (char*)d_ws;
  float*        score   = (float*)(ws + OFF_SCORE);
  unsigned int* ctrs    = (unsigned int*)(ws + OFF_CTR);
  bf16*         Cpub    = (bf16*)(ws + OFF_CPUB0);   // [2][128][1024], buf0 zeroed
  float*        G       = (float*)(ws + OFF_G);
  float*        bias_r  = (float*)(ws + OFF_BIASR);
  float*        Cfin    = (float*)(ws + OFF_CFIN);
  bf16*         concat  = (bf16*)(ws + OFF_CONCAT);
  bf16*         facts_b = (bf16*)(ws + OFF_FACTS);
  bf16*         Wz1_b   = (bf16*)(ws + OFF_WZ1);
  bf16*         WrW_b   = (bf16*)(ws + OFF_WRW);
  bf16*         UrU_b   = (bf16*)(ws + OFF_URU);
  bf16*         Wm_b    = (bf16*)(ws + OFF_WM);
  bf16*         P       = (bf16*)(ws + OFF_P);

  hipMemsetAsync(ws, 0, ZERO_BYTES, stream);   // score + counters + Cpub0

  // bf16 casts
  cast_f32_bf16<<<16384, 256, 0, stream>>>(facts, facts_b, 16777216);
  cast_f32_bf16<<< 4096, 256, 0, stream>>>(Wz1, Wz1_b, 4194304);
  cast_f32_bf16<<< 1024, 256, 0, stream>>>(Wr, WrW_b,           1048576);
  cast_f32_bf16<<< 1024, 256, 0, stream>>>(Wf, WrW_b + 1048576, 1048576);
  cast_f32_bf16<<< 1024, 256, 0, stream>>>(Ur, UrU_b,           1048576);
  cast_f32_bf16<<< 1024, 256, 0, stream>>>(U,  UrU_b + 1048576, 1048576);
  cast_f32_bf16<<< 3072, 256, 0, stream>>>(Wm, Wm_b, 3145728);
  add_bias_k<<<4, 256, 0, stream>>>(br, bur, bias_r);

  // gate: scores, then softmax -> G
  gate_gemm<<<dim3(8, 128), 256, 0, stream>>>(facts, questions, prevM, Wz1_b, bz1, Wz2, score);
  softmax128<<<128, 128, 0, stream>>>(score, G);

  // fact projections P[s][b][0:2048] = facts @ [Wr;W]^T
  gemm_bt<0><<<dim3(16, 128), 256, 0, stream>>>(facts_b, WrW_b, 1024, P, nullptr, nullptr);

  // sequential scan
  scan_kernel<<<256, 256, 0, stream>>>(UrU_b, P, G, bias_r, bw, bu, Cpub, Cfin, ctrs);

  // final: relu(concat @ Wm^T + bm)
  build_concat<<<384, 256, 0, stream>>>(prevM, Cfin, questions, concat);
  gemm_bt<1><<<dim3(8, 1), 256, 0, stream>>>(concat, Wm_b, 3072, nullptr, bm, out);
}

// Round 2
// 1100.456 us; speedup vs baseline: 2.5112x; 2.5112x over previous
//
#include <hip/hip_runtime.h>
#include <hip/hip_bf16.h>

typedef __attribute__((ext_vector_type(8))) short short8;
typedef __attribute__((ext_vector_type(4))) short short4v;
typedef __attribute__((ext_vector_type(4))) float floatx4;
typedef __attribute__((ext_vector_type(4))) unsigned int uint4v;

using bf16 = __hip_bfloat16;

#define DEVI __device__ __forceinline__

// ---------------- workspace layout (bytes) ----------------
static constexpr size_t OFF_SCORE  = 0;                        // 128*128 f32
static constexpr size_t OFF_CTR    = OFF_SCORE  + 65536;       // 8*128 u32
static constexpr size_t OFF_CPUB0  = OFF_CTR    + 4096;        // 128*1024 bf16
static constexpr size_t OFF_CPUB1  = OFF_CPUB0  + 262144;
static constexpr size_t ZERO_BYTES = OFF_CPUB1;                // score+ctr+Cpub0 zeroed
static constexpr size_t OFF_G      = OFF_CPUB1  + 262144;      // 128*128 f32
static constexpr size_t OFF_BIASR  = OFF_G      + 65536;       // 1024 f32
static constexpr size_t OFF_CFIN   = OFF_BIASR  + 4096;        // 128*1024 f32
static constexpr size_t OFF_CONCAT = OFF_CFIN   + 524288;      // 128*3072 bf16
static constexpr size_t OFF_FACTS  = OFF_CONCAT + 786432;      // 16M bf16
static constexpr size_t OFF_WZ1    = OFF_FACTS  + 33554432ull; // 1024*4096 bf16
static constexpr size_t OFF_WRW    = OFF_WZ1    + 8388608ull;  // 2048*1024 bf16
static constexpr size_t OFF_URU    = OFF_WRW    + 4194304ull;  // 2048*1024 bf16
static constexpr size_t OFF_WM     = OFF_URU    + 4194304ull;  // 1024*3072 bf16
static constexpr size_t OFF_P      = OFF_WM     + 6291456ull;  // 128*128*2048 bf16

DEVI float sigm_f(float x){ return 1.f/(1.f + __expf(-x)); }
DEVI float tanh_f(float x){ float e = __expf(2.f*x); return 1.f - 2.f/(e + 1.f); }

// ---- coherent-point (sc0 sc1) access helpers: no L2 maintenance ops needed ----
DEVI unsigned long long ld_cg_u64(const unsigned long long* p){
  unsigned long long r;
  asm volatile("global_load_dwordx2 %0, %1, off sc0 sc1" : "=v"(r) : "v"(p) : "memory");
  return r;
}
DEVI void st_cg_u32(unsigned int* p, unsigned int v){
  asm volatile("global_store_dword %0, %1, off sc0 sc1" : : "v"(p), "v"(v) : "memory");
}
DEVI void waitcnt_vm0(){ asm volatile("s_waitcnt vmcnt(0)" ::: "memory"); }

// ---------------- small utility kernels ----------------
__global__ void cast_f32_bf16(const float* __restrict__ src, bf16* __restrict__ dst, int n){
  int i = (blockIdx.x*256 + threadIdx.x)*4;
  if (i >= n) return;
  float4 v = *(const float4*)(src + i);
  union { bf16 h[4]; short4v s; } u;
  u.h[0] = __float2bfloat16(v.x); u.h[1] = __float2bfloat16(v.y);
  u.h[2] = __float2bfloat16(v.z); u.h[3] = __float2bfloat16(v.w);
  *(short4v*)(dst + i) = u.s;
}

__global__ void add_bias_k(const float* __restrict__ a, const float* __restrict__ b, float* __restrict__ o){
  int i = blockIdx.x*256 + threadIdx.x;
  if (i < 1024) o[i] = a[i] + b[i];
}

__global__ void softmax128(const float* __restrict__ score, float* __restrict__ G){
  int b = blockIdx.x, t = threadIdx.x;
  int lane = t & 63, wv = t >> 6;
  float v = score[b*128 + t];
  float mx = v;
  #pragma unroll
  for (int m = 1; m < 64; m <<= 1) mx = fmaxf(mx, __shfl_xor(mx, m));
  __shared__ float r1[2], r2[2];
  if (lane == 0) r1[wv] = mx;
  __syncthreads();
  mx = fmaxf(r1[0], r1[1]);
  float e = __expf(v - mx);
  float sm = e;
  #pragma unroll
  for (int m = 1; m < 64; m <<= 1) sm += __shfl_xor(sm, m);
  if (lane == 0) r2[wv] = sm;
  __syncthreads();
  sm = r2[0] + r2[1];
  G[b*128 + t] = e / sm;
}

__global__ void build_concat(const float* __restrict__ prevM, const float* __restrict__ Cfin,
                             const float* __restrict__ q, bf16* __restrict__ out){
  int i = (blockIdx.x*256 + threadIdx.x)*4;   // n = 128*3072
  if (i >= 128*3072) return;
  int b = i / 3072, k = i % 3072;
  const float* src = (k < 1024) ? (prevM + b*1024 + k)
                   : (k < 2048) ? (Cfin + b*1024 + (k-1024))
                                : (q    + b*1024 + (k-2048));
  float4 v = *(const float4*)src;
  union { bf16 h[4]; short4v s; } u;
  u.h[0] = __float2bfloat16(v.x); u.h[1] = __float2bfloat16(v.y);
  u.h[2] = __float2bfloat16(v.z); u.h[3] = __float2bfloat16(v.w);
  *(short4v*)(out + i) = u.s;
}

// ---------------- gate GEMM: z on-the-fly, fused tanh + Wz2 reduction ----------------
__global__ __launch_bounds__(256, 2) void gate_gemm(
    const float* __restrict__ facts, const float* __restrict__ q,
    const float* __restrict__ pm, const bf16* __restrict__ Wz1b,
    const float* __restrict__ bz1, const float* __restrict__ wz2,
    float* __restrict__ score)
{
  constexpr int TS = 80;
  __shared__ bf16 As[128*TS];
  __shared__ bf16 Bs[128*TS];
  __shared__ float qs[1024];
  __shared__ float ms[1024];
  int tid = threadIdx.x;
  int b  = blockIdx.y;
  int n0 = blockIdx.x * 128;
  int w = tid >> 6, lane = tid & 63;
  int wm = w >> 1, wn = w & 1;
  int quad = lane >> 4, col = lane & 15;

  for (int i = tid; i < 1024; i += 256){ qs[i] = q[b*1024 + i]; ms[i] = pm[b*1024 + i]; }
  __syncthreads();

  floatx4 acc[4][4];
  #pragma unroll
  for (int a = 0; a < 4; ++a)
    #pragma unroll
    for (int c = 0; c < 4; ++c) acc[a][c] = (floatx4){0.f,0.f,0.f,0.f};

  for (int it = 0; it < 64; ++it){
    int k0 = it * 64;
    int qd = k0 >> 10;
    int kk0 = k0 & 1023;
    #pragma unroll
    for (int i = 0; i < 4; ++i){
      int c = tid + i*256;
      int r = c >> 3, cc = c & 7;
      int kk = kk0 + cc*8;
      const float* fp = facts + (size_t)(b*128 + r)*1024 + kk;
      float f[8], aux[8];
      *(float4*)(f)   = *(const float4*)(fp);
      *(float4*)(f+4) = *(const float4*)(fp + 4);
      const float* av = (qd == 0 || qd == 2) ? qs : ms;
      *(float4*)(aux)   = *(const float4*)(av + kk);
      *(float4*)(aux+4) = *(const float4*)(av + kk + 4);
      union { bf16 h[8]; short8 s8; } u;
      if (qd < 2){
        #pragma unroll
        for (int j = 0; j < 8; ++j) u.h[j] = __float2bfloat16(f[j]*aux[j]);
      } else {
        #pragma unroll
        for (int j = 0; j < 8; ++j) u.h[j] = __float2bfloat16(fabsf(f[j]-aux[j]));
      }
      *(short8*)&As[r*TS + cc*8] = u.s8;
    }
    #pragma unroll
    for (int i = 0; i < 4; ++i){
      int c = tid + i*256;
      int r = c >> 3, cc = c & 7;
      *(uint4v*)&Bs[r*TS + cc*8] = *(const uint4v*)(Wz1b + (size_t)(n0 + r)*4096 + k0 + cc*8);
    }
    __syncthreads();
    #pragma unroll
    for (int kt = 0; kt < 2; ++kt){
      short8 af[4], bfv[4];
      #pragma unroll
      for (int mt = 0; mt < 4; ++mt)
        af[mt] = *(const short8*)&As[(wm*64 + mt*16 + col)*TS + kt*32 + quad*8];
      #pragma unroll
      for (int nt = 0; nt < 4; ++nt)
        bfv[nt] = *(const short8*)&Bs[(wn*64 + nt*16 + col)*TS + kt*32 + quad*8];
      #pragma unroll
      for (int mt = 0; mt < 4; ++mt)
        #pragma unroll
        for (int nt = 0; nt < 4; ++nt)
          acc[mt][nt] = __builtin_amdgcn_mfma_f32_16x16x32_bf16(af[mt], bfv[nt], acc[mt][nt], 0,0,0);
    }
    __syncthreads();
  }
  #pragma unroll
  for (int mt = 0; mt < 4; ++mt){
    float part[4] = {0.f,0.f,0.f,0.f};
    #pragma unroll
    for (int nt = 0; nt < 4; ++nt){
      int n = n0 + wn*64 + nt*16 + col;
      float b1 = bz1[n], w2 = wz2[n];
      #pragma unroll
      for (int rr = 0; rr < 4; ++rr)
        part[rr] += tanh_f(acc[mt][nt][rr] + b1) * w2;
    }
    #pragma unroll
    for (int rr = 0; rr < 4; ++rr){
      float p = part[rr];
      p += __shfl_xor(p, 1); p += __shfl_xor(p, 2);
      p += __shfl_xor(p, 4); p += __shfl_xor(p, 8);
      if (col == 0)
        atomicAdd(&score[b*128 + wm*64 + mt*16 + quad*4 + rr], p);
    }
  }
}

// ---------------- generic 128x128 bf16 GEMM (B^T layout) ----------------
template<int MODE>
__global__ __launch_bounds__(256, 2) void gemm_bt(
    const bf16* __restrict__ A, const bf16* __restrict__ Bm, int K,
    bf16* __restrict__ Pout, const float* __restrict__ bias, float* __restrict__ out)
{
  constexpr int TS = 80;
  __shared__ bf16 As[128*TS];
  __shared__ bf16 Bs[128*TS];
  int tid = threadIdx.x;
  int m0 = blockIdx.y * 128, n0 = blockIdx.x * 128;
  int w = tid >> 6, lane = tid & 63;
  int wm = w >> 1, wn = w & 1;
  int quad = lane >> 4, col = lane & 15;

  floatx4 acc[4][4];
  #pragma unroll
  for (int a = 0; a < 4; ++a)
    #pragma unroll
    for (int c = 0; c < 4; ++c) acc[a][c] = (floatx4){0.f,0.f,0.f,0.f};

  int nkb = K >> 6;
  for (int it = 0; it < nkb; ++it){
    int k0 = it * 64;
    #pragma unroll
    for (int i = 0; i < 4; ++i){
      int c = tid + i*256;
      int r = c >> 3, cc = c & 7;
      *(uint4v*)&As[r*TS + cc*8] = *(const uint4v*)(A  + (size_t)(m0 + r)*K + k0 + cc*8);
      *(uint4v*)&Bs[r*TS + cc*8] = *(const uint4v*)(Bm + (size_t)(n0 + r)*K + k0 + cc*8);
    }
    __syncthreads();
    #pragma unroll
    for (int kt = 0; kt < 2; ++kt){
      short8 af[4], bfv[4];
      #pragma unroll
      for (int mt = 0; mt < 4; ++mt)
        af[mt] = *(const short8*)&As[(wm*64 + mt*16 + col)*TS + kt*32 + quad*8];
      #pragma unroll
      for (int nt = 0; nt < 4; ++nt)
        bfv[nt] = *(const short8*)&Bs[(wn*64 + nt*16 + col)*TS + kt*32 + quad*8];
      #pragma unroll
      for (int mt = 0; mt < 4; ++mt)
        #pragma unroll
        for (int nt = 0; nt < 4; ++nt)
          acc[mt][nt] = __builtin_amdgcn_mfma_f32_16x16x32_bf16(af[mt], bfv[nt], acc[mt][nt], 0,0,0);
    }
    __syncthreads();
  }
  #pragma unroll
  for (int mt = 0; mt < 4; ++mt)
    #pragma unroll
    for (int nt = 0; nt < 4; ++nt)
      #pragma unroll
      for (int rr = 0; rr < 4; ++rr){
        int m = m0 + wm*64 + mt*16 + quad*4 + rr;
        int n = n0 + wn*64 + nt*16 + col;
        float v = acc[mt][nt][rr];
        if (MODE == 0){
          Pout[((size_t)(m & 127)*128 + (m >> 7))*2048 + n] = __float2bfloat16(v);
        } else {
          out[(size_t)m*1024 + n] = fmaxf(v + bias[n], 0.f);
        }
      }
}

// ---------------- the sequential scan ----------------
// 256 blocks = 8 batch-groups (16 batches) x 32 column-blocks (32 cols).
// Fence-free coherent-point protocol: C publish via sc0sc1 stores, staging via
// sc0sc1 loads, per-block relaxed atomic flag; NO agent fences (no L2 flushes).
__global__ __launch_bounds__(256, 1) void scan_kernel(
    const bf16* __restrict__ UrU, const bf16* __restrict__ P,
    const float* __restrict__ G, const float* __restrict__ bias_r,
    const float* __restrict__ bw, const float* __restrict__ bu,
    bf16* __restrict__ Cpub, float* __restrict__ Cfinal,
    unsigned int* __restrict__ counters)
{
  constexpr int CS = 1040;               // padded LDS stride (bf16), 16B-aligned
  __shared__ bf16 Cs[16*CS];
  __shared__ float Qex[2*16*32];         // [matrix][batch][col]
  int tid = threadIdx.x;
  int g  = blockIdx.x >> 5;              // batch group 0..7
  int nb = blockIdx.x & 31;              // column block 0..31
  int b0 = g * 16, j0 = nb * 32;
  int w = tid >> 6, lane = tid & 63;
  int quad = lane >> 4, col = lane & 15;

  // B-fragments in registers: wave w -> matrix (w>>1), n-half (w&1)
  short8 bfrag[32];
  {
    int n = ((w >> 1) << 10) + j0 + ((w & 1) << 4) + col;
    const bf16* src = UrU + (size_t)n*1024 + (quad << 3);
    #pragma unroll
    for (int kt = 0; kt < 32; ++kt) bfrag[kt] = *(const short8*)(src + kt*32);
  }

  int r  = tid >> 4;                     // batch row 0..15
  int jp = (tid & 15) * 2;               // col pair
  float c0 = 0.f, c1 = 0.f;
  float2 brv = *(const float2*)(bias_r + j0 + jp);
  float2 bwv = *(const float2*)(bw     + j0 + jp);
  float2 buv = *(const float2*)(bu     + j0 + jp);
  unsigned int* ctr = counters + g*128;

  for (int s = 0; s < 128; ++s){
    // prefetch P/G for this step (independent of the barrier)
    const bf16* Ps = P + (size_t)s*(128*2048) + (size_t)(b0 + r)*2048 + j0 + jp;
    unsigned int up1 = *(const unsigned int*)Ps;
    unsigned int up2 = *(const unsigned int*)(Ps + 1024);
    float gg = G[(b0 + r)*128 + s];

    // wave-level wait for previous step's publications
    if (s){
      if (lane == 0){
        int probe = 0;
        for (;;){
          unsigned int c;
          if ((++probe & 15) == 0)
            c = __hip_atomic_fetch_add(&ctr[s-1], 0u, __ATOMIC_RELAXED, __HIP_MEMORY_SCOPE_AGENT);
          else
            c = __hip_atomic_load(&ctr[s-1], __ATOMIC_RELAXED, __HIP_MEMORY_SCOPE_AGENT);
          if (c >= 32u) break;
          __builtin_amdgcn_s_sleep(1);
        }
      }
    }

    // stage this group's C (16 x 1024 bf16 = 4096 u64) from the coherent point
    const unsigned long long* Cg =
      (const unsigned long long*)(Cpub + (size_t)(s & 1)*(128*1024) + b0*1024);
    unsigned long long vv[16];
    #pragma unroll
    for (int i = 0; i < 16; ++i) vv[i] = ld_cg_u64(Cg + tid + i*256);
    waitcnt_vm0();
    #pragma unroll
    for (int i = 0; i < 16; ++i){
      int slot = tid + i*256;
      int rr = slot >> 8, cc = slot & 255;     // 256 u64 per row
      *(unsigned long long*)&Cs[rr*CS + cc*4] = vv[i];
    }
    __syncthreads();

    // Q = C @ [Ur;U]^T (this block's 32 cols), two independent MFMA chains
    floatx4 a0 = (floatx4){0.f,0.f,0.f,0.f}, a1 = (floatx4){0.f,0.f,0.f,0.f};
    {
      const bf16* Ap = Cs + col*CS + (quad << 3);
      #pragma unroll
      for (int kt = 0; kt < 16; ++kt){
        short8 a = *(const short8*)(Ap + kt*32);
        a0 = __builtin_amdgcn_mfma_f32_16x16x32_bf16(a, bfrag[kt], a0, 0,0,0);
      }
      #pragma unroll
      for (int kt = 16; kt < 32; ++kt){
        short8 a = *(const short8*)(Ap + kt*32);
        a1 = __builtin_amdgcn_mfma_f32_16x16x32_bf16(a, bfrag[kt], a1, 0,0,0);
      }
    }
    {
      int mi = w >> 1, nh = w & 1;
      #pragma unroll
      for (int rr = 0; rr < 4; ++rr)
        Qex[mi*512 + (quad*4 + rr)*32 + nh*16 + col] = a0[rr] + a1[rr];
    }
    __syncthreads();

    // elementwise GRU-style update: thread owns (batch r, cols jp,jp+1)
    float p1a = __bfloat162float(*(const bf16*)&up1);
    float p1b = __bfloat162float(*((const bf16*)&up1 + 1));
    float p2a = __bfloat162float(*(const bf16*)&up2);
    float p2b = __bfloat162float(*((const bf16*)&up2 + 1));
    float2 q1 = *(const float2*)&Qex[r*32 + jp];
    float2 q2 = *(const float2*)&Qex[512 + r*32 + jp];
    float ra = sigm_f(p1a + q1.x + brv.x);
    float ha = tanh_f(p2a + bwv.x + ra*(q2.x + buv.x));
    c0 = gg*ha + (1.f - gg)*c0;
    float rb = sigm_f(p1b + q1.y + brv.y);
    float hb = tanh_f(p2b + bwv.y + rb*(q2.y + buv.y));
    c1 = gg*hb + (1.f - gg)*c1;

    if (s != 127){
      union { bf16 h[2]; unsigned int u; } pk;
      pk.h[0] = __float2bfloat16(c0);
      pk.h[1] = __float2bfloat16(c1);
      unsigned int* dst = (unsigned int*)
        (Cpub + (size_t)((s & 1) ^ 1)*(128*1024) + (size_t)(b0 + r)*1024 + j0 + jp);
      st_cg_u32(dst, pk.u);
      waitcnt_vm0();                      // store ack'd at coherent point
      __syncthreads();                    // whole block published
      if (tid == 0)
        __hip_atomic_fetch_add(&ctr[s], 1u, __ATOMIC_RELAXED, __HIP_MEMORY_SCOPE_AGENT);
    }
  }
  *(float2*)&Cfinal[(size_t)(b0 + r)*1024 + j0 + jp] = make_float2(c0, c1);
}

// ---------------- host launch ----------------
extern "C" void kernel_launch(void* const* d_in, const int* in_sizes, int n_in,
                              void* d_out, int out_size, void* d_ws, size_t ws_size,
                              hipStream_t stream) {
  const float* facts     = (const float*)d_in[0];
  const float* questions = (const float*)d_in[1];
  const float* prevM     = (const float*)d_in[2];
  const float* Wr        = (const float*)d_in[3];
  const float* br        = (const float*)d_in[4];
  const float* Ur        = (const float*)d_in[5];
  const float* bur       = (const float*)d_in[6];
  const float* Wf        = (const float*)d_in[7];
  const float* bw        = (const float*)d_in[8];
  const float* U         = (const float*)d_in[9];
  const float* bu        = (const float*)d_in[10];
  const float* Wz1       = (const float*)d_in[11];
  const float* bz1       = (const float*)d_in[12];
  const float* Wz2       = (const float*)d_in[13];
  const float* Wm        = (const float*)d_in[15];
  const float* bm        = (const float*)d_in[16];
  float* out = (float*)d_out;

  char* ws = (char*)d_ws;
  float*        score   = (float*)(ws + OFF_SCORE);
  unsigned int* ctrs    = (unsigned int*)(ws + OFF_CTR);
  bf16*         Cpub    = (bf16*)(ws + OFF_CPUB0);
  float*        G       = (float*)(ws + OFF_G);
  float*        bias_r  = (float*)(ws + OFF_BIASR);
  float*        Cfin    = (float*)(ws + OFF_CFIN);
  bf16*         concat  = (bf16*)(ws + OFF_CONCAT);
  bf16*         facts_b = (bf16*)(ws + OFF_FACTS);
  bf16*         Wz1_b   = (bf16*)(ws + OFF_WZ1);
  bf16*         WrW_b   = (bf16*)(ws + OFF_WRW);
  bf16*         UrU_b   = (bf16*)(ws + OFF_URU);
  bf16*         Wm_b    = (bf16*)(ws + OFF_WM);
  bf16*         P       = (bf16*)(ws + OFF_P);

  hipMemsetAsync(ws, 0, ZERO_BYTES, stream);

  cast_f32_bf16<<<16384, 256, 0, stream>>>(facts, facts_b, 16777216);
  cast_f32_bf16<<< 4096, 256, 0, stream>>>(Wz1, Wz1_b, 4194304);
  cast_f32_bf16<<< 1024, 256, 0, stream>>>(Wr, WrW_b,           1048576);
  cast_f32_bf16<<< 1024, 256, 0, stream>>>(Wf, WrW_b + 1048576, 1048576);
  cast_f32_bf16<<< 1024, 256, 0, stream>>>(Ur, UrU_b,           1048576);
  cast_f32_bf16<<< 1024, 256, 0, stream>>>(U,  UrU_b + 1048576, 1048576);
  cast_f32_bf16<<< 3072, 256, 0, stream>>>(Wm, Wm_b, 3145728);
  add_bias_k<<<4, 256, 0, stream>>>(br, bur, bias_r);

  gate_gemm<<<dim3(8, 128), 256, 0, stream>>>(facts, questions, prevM, Wz1_b, bz1, Wz2, score);
  softmax128<<<128, 128, 0, stream>>>(score, G);

  gemm_bt<0><<<dim3(16, 128), 256, 0, stream>>>(facts_b, WrW_b, 1024, P, nullptr, nullptr);

  scan_kernel<<<256, 256, 0, stream>>>(UrU_b, P, G, bias_r, bw, bu, Cpub, Cfin, ctrs);

  build_concat<<<384, 256, 0, stream>>>(prevM, Cfin, questions, concat);
  gemm_bt<1><<<dim3(8, 1), 256, 0, stream>>>(concat, Wm_b, 3072, nullptr, bm, out);
}